// Round 3
// baseline (1179.767 us; speedup 1.0000x reference)
//
#include <hip/hip_runtime.h>
#include <hip/hip_bf16.h>

#define GNUM 64
#define BN_EPS 1e-5f

typedef unsigned short u16;
typedef unsigned int u32;
typedef __attribute__((ext_vector_type(8))) short short8;
typedef __attribute__((ext_vector_type(4))) float f32x4;

__device__ inline float bflo(u32 u) { union { u32 i; float f; } v; v.i = u << 16; return v.f; }
__device__ inline float bfhi(u32 u) { union { u32 i; float f; } v; v.i = u & 0xFFFF0000u; return v.f; }
__device__ inline u16 f2bf(float f) {
    union { float f; u32 i; } v; v.f = f;
    u32 x = v.i;
    return (u16)((x + 0x7FFFu + ((x >> 16) & 1u)) >> 16);  // RNE
}
__device__ inline u32 pack2(float a, float b) { return (u32)f2bf(a) | ((u32)f2bf(b) << 16); }

// ---------------- zero-init (no hipMemsetAsync) ----------------
__global__ void zero_f(float* __restrict__ p, int n) {
    int i = blockIdx.x * 256 + threadIdx.x;
    if (i < n) p[i] = 0.f;
}
__global__ void zero_i(int* __restrict__ p, int n) {
    int i = blockIdx.x * 256 + threadIdx.x;
    if (i < n) p[i] = 0;
}

// ---------------- CSR build ----------------
__global__ void deg_kernel(const int* __restrict__ dst, int* __restrict__ deg, int E) {
    int e = blockIdx.x * 256 + threadIdx.x;
    if (e < E) atomicAdd(&deg[dst[e]], 1);
}

__global__ void scan_block(const int* __restrict__ deg, int* __restrict__ part,
                           int* __restrict__ bsum, int n) {
    __shared__ int tmp[256];
    int i = blockIdx.x * 256 + threadIdx.x;
    int v = (i < n) ? deg[i] : 0;
    tmp[threadIdx.x] = v;
    __syncthreads();
    for (int off = 1; off < 256; off <<= 1) {
        int x = 0;
        if (threadIdx.x >= off) x = tmp[threadIdx.x - off];
        __syncthreads();
        tmp[threadIdx.x] += x;
        __syncthreads();
    }
    if (i < n) part[i] = tmp[threadIdx.x];
    if (threadIdx.x == 255) bsum[blockIdx.x] = tmp[255];
}

__global__ void scan_bsum(int* __restrict__ bsum, int nb) {
    __shared__ int tmp[256];
    int v = (threadIdx.x < nb) ? bsum[threadIdx.x] : 0;
    tmp[threadIdx.x] = v;
    __syncthreads();
    for (int off = 1; off < 256; off <<= 1) {
        int x = 0;
        if (threadIdx.x >= off) x = tmp[threadIdx.x - off];
        __syncthreads();
        tmp[threadIdx.x] += x;
        __syncthreads();
    }
    if (threadIdx.x < nb) bsum[threadIdx.x] = tmp[threadIdx.x];
}

__global__ void scan_fix(const int* __restrict__ part, const int* __restrict__ bsum,
                         int* __restrict__ offs, int* __restrict__ cursor, int n) {
    int i = blockIdx.x * 256 + threadIdx.x;
    if (i >= n) return;
    int add = (blockIdx.x > 0) ? bsum[blockIdx.x - 1] : 0;
    int incl = part[i] + add;
    offs[i + 1] = incl;
    cursor[i + 1] = incl;
    if (i == 0) { offs[0] = 0; cursor[0] = 0; }
}

__global__ void fill_kernel(const int* __restrict__ src, const int* __restrict__ dst,
                            int* __restrict__ cursor, int* __restrict__ eidx, int E) {
    int e = blockIdx.x * 256 + threadIdx.x;
    if (e >= E) return;
    int d = dst[e];
    int p = atomicAdd(&cursor[d], 1);
    eidx[p] = src[e];
}

// per-graph node counts (batch sorted -> run-length + atomic per run)
__global__ void cnt_kernel(const int* __restrict__ batch, float* __restrict__ cnt, int Nn) {
    int tid = blockIdx.x * blockDim.x + threadIdx.x;
    int s = tid * 64;
    if (s >= Nn) return;
    int e = min(s + 64, Nn);
    int cur = batch[s]; int run = 0;
    for (int r = s; r < e; ++r) {
        int b = batch[r];
        if (b != cur) { atomicAdd(&cnt[cur], (float)run); cur = b; run = 0; }
        run++;
    }
    atomicAdd(&cnt[cur], (float)run);
}

// ---------------- weight convert+transpose: Wt[n*K+k] = bf16(W[k*256+n]) ----------------
__global__ void transw(const float* __restrict__ src, u16* __restrict__ dst, int K) {
    int idx = blockIdx.x * 256 + threadIdx.x;
    if (idx >= K * 256) return;
    int k = idx >> 8, n = idx & 255;
    dst[n * K + k] = f2bf(src[idx]);
}

// ---------------- aggregation layer 0: fp32 x[N,128] -> bf16 z ----------------
__global__ void agg_f32(const float* __restrict__ h, const int* __restrict__ offs,
                        const int* __restrict__ eidx, u16* __restrict__ z, int Nn) {
    int n = blockIdx.x;                 // one block per node, 64 threads
    int c = threadIdx.x << 1;           // 2 cols per thread (F=128)
    float2 a = *(const float2*)&h[(size_t)n * 128 + c];
    int j1 = offs[n + 1];
    for (int j = offs[n]; j < j1; ++j) {
        int s = eidx[j];
        float2 w = *(const float2*)&h[(size_t)s * 128 + c];
        a.x += w.x; a.y += w.y;
    }
    *(u32*)&z[(size_t)n * 128 + c] = pack2(a.x, a.y);
}

// ---------------- aggregation layers 1-3: bf16 h[N,256] -> bf16 z ----------------
__global__ void agg_bf16(const u16* __restrict__ h, const int* __restrict__ offs,
                         const int* __restrict__ eidx, u16* __restrict__ z, int Nn) {
    int n = blockIdx.x;                 // one block per node, 128 threads
    int c = threadIdx.x << 1;
    u32 u = *(const u32*)&h[(size_t)n * 256 + c];
    float a0 = bflo(u), a1 = bfhi(u);
    int j1 = offs[n + 1];
    for (int j = offs[n]; j < j1; ++j) {
        int s = eidx[j];
        u32 w = *(const u32*)&h[(size_t)s * 256 + c];
        a0 += bflo(w); a1 += bfhi(w);
    }
    *(u32*)&z[(size_t)n * 256 + c] = pack2(a0, a1);
}

// ---------------- MFMA bf16 GEMM: C[M,256] = (relu?)(A[M,K] @ W[K,256] + b) ----------------
// Wt is W transposed bf16: Wt[n*K+k]. Tile 128x128, 4 waves 2x2, each wave 4x4 of 16x16x32.
template<int K, bool RELU>
__global__ __launch_bounds__(256)
void gemm_mfma(const u16* __restrict__ A, const u16* __restrict__ Wt,
               const float* __restrict__ bias, u16* __restrict__ C, int M) {
    __shared__ u16 As[128 * 32];
    __shared__ u16 Bs[128 * 32];
    int t = threadIdx.x;
    int m0 = blockIdx.x * 128;
    int n0 = blockIdx.y * 128;
    int lane = t & 63, wave = t >> 6;
    int wm = (wave & 1) << 6, wn = (wave >> 1) << 6;
    int lm = lane & 15, q = lane >> 4;

    f32x4 acc[4][4];
#pragma unroll
    for (int i = 0; i < 4; ++i)
#pragma unroll
        for (int j = 0; j < 4; ++j) acc[i][j] = (f32x4)0.0f;

    for (int k0 = 0; k0 < K; k0 += 32) {
        __syncthreads();
#pragma unroll
        for (int i = 0; i < 2; ++i) {
            int idx = t + i * 256;
            int r = idx >> 2, ko = (idx & 3) << 3;
            int gr = m0 + r;
            uint4 av = make_uint4(0u, 0u, 0u, 0u);
            if (gr < M) av = *(const uint4*)&A[(size_t)gr * K + k0 + ko];
            *(uint4*)&As[r * 32 + ko] = av;
            uint4 bv = *(const uint4*)&Wt[(size_t)(n0 + r) * K + k0 + ko];
            *(uint4*)&Bs[r * 32 + ko] = bv;
        }
        __syncthreads();
        short8 af[4], bfr[4];
#pragma unroll
        for (int i = 0; i < 4; ++i) {
            af[i]  = *(const short8*)&As[(wm + i * 16 + lm) * 32 + q * 8];
            bfr[i] = *(const short8*)&Bs[(wn + i * 16 + lm) * 32 + q * 8];
        }
#pragma unroll
        for (int i = 0; i < 4; ++i)
#pragma unroll
            for (int j = 0; j < 4; ++j)
                acc[i][j] = __builtin_amdgcn_mfma_f32_16x16x32_bf16(af[i], bfr[j], acc[i][j], 0, 0, 0);
    }

    // C/D layout (m89-verified): col = lane&15, row = (lane>>4)*4 + reg
#pragma unroll
    for (int j = 0; j < 4; ++j) {
        int col = n0 + wn + j * 16 + lm;
        float bv = bias[col];
#pragma unroll
        for (int i = 0; i < 4; ++i) {
#pragma unroll
            for (int r = 0; r < 4; ++r) {
                int row = m0 + wm + i * 16 + q * 4 + r;
                if (row < M) {
                    float v = acc[i][j][r] + bv;
                    if (RELU) v = fmaxf(v, 0.f);
                    C[(size_t)row * 256 + col] = f2bf(v);
                }
            }
        }
    }
}

// ---------------- BN stats: per-column sum/sumsq ----------------
__global__ __launch_bounds__(256)
void bn_stats(const u16* __restrict__ Z, float* __restrict__ stats, int Nn) {
    int col = threadIdx.x;
    float s = 0.f, q = 0.f;
    for (int r = blockIdx.x; r < Nn; r += gridDim.x) {
        float v = bflo(Z[(size_t)r * 256 + col]);
        s += v; q = fmaf(v, v, q);
    }
    atomicAdd(&stats[col], s);
    atomicAdd(&stats[256 + col], q);
}

// ---------------- BN apply + ReLU + segmented max/sum pool ----------------
__global__ __launch_bounds__(256)
void bn_pool(const u16* __restrict__ Z, const float* __restrict__ stats,
             const float* __restrict__ gamma, const float* __restrict__ beta,
             const int* __restrict__ batch, u16* __restrict__ H,
             float* __restrict__ pool_max, float* __restrict__ pool_sum, int Nn) {
    int col = threadIdx.x;
    int r0 = blockIdx.x * 64;
    if (r0 >= Nn) return;
    float mu = stats[col] / (float)Nn;
    float var = stats[256 + col] / (float)Nn - mu * mu;
    float scale = gamma[col] * rsqrtf(var + BN_EPS);
    float shift = beta[col] - mu * scale;
    int rend = min(r0 + 64, Nn);
    int cur = batch[r0];
    float rmax = 0.f, rsum = 0.f;
    for (int r = r0; r < rend; ++r) {
        int bb = batch[r];
        if (bb != cur) {
            atomicMax((int*)&pool_max[cur * 256 + col], __float_as_int(rmax));
            atomicAdd(&pool_sum[cur * 256 + col], rsum);
            cur = bb; rmax = 0.f; rsum = 0.f;
        }
        float v = fmaf(bflo(Z[(size_t)r * 256 + col]), scale, shift);
        v = fmaxf(v, 0.f);  // ReLU; >=0 so int atomicMax on float bits is valid
        H[(size_t)r * 256 + col] = f2bf(v);
        rmax = fmaxf(rmax, v); rsum += v;
    }
    atomicMax((int*)&pool_max[cur * 256 + col], __float_as_int(rmax));
    atomicAdd(&pool_sum[cur * 256 + col], rsum);
}

// ---------------- acc += concat(max, mean) ----------------
__global__ void acc_update(const float* __restrict__ pmax, const float* __restrict__ psum,
                           const float* __restrict__ cnt, float* __restrict__ acc) {
    int i = blockIdx.x * 256 + threadIdx.x;  // GNUM*512 total
    int g = i >> 9, c = i & 511;
    float v = (c < 256) ? pmax[g * 256 + c]
                        : psum[g * 256 + (c - 256)] / fmaxf(cnt[g], 1.f);
    acc[i] += v;
}

// ---------------- fused readout MLP (fp32): [64,512]->256->128->250 ----------------
__global__ __launch_bounds__(256)
void readout_kernel(const float* __restrict__ acc,
                    const float* __restrict__ w1, const float* __restrict__ b1,
                    const float* __restrict__ w2, const float* __restrict__ b2,
                    const float* __restrict__ w3, const float* __restrict__ b3,
                    float* __restrict__ out) {
    __shared__ float a[512], z1[256], z2[128];
    int g = blockIdx.x, t = threadIdx.x;
    a[t] = acc[g * 512 + t];
    a[t + 256] = acc[g * 512 + 256 + t];
    __syncthreads();
    float s = b1[t];
    for (int k = 0; k < 512; ++k) s = fmaf(a[k], w1[k * 256 + t], s);
    z1[t] = fmaxf(s, 0.f);
    __syncthreads();
    if (t < 128) {
        float s2 = b2[t];
        for (int k = 0; k < 256; ++k) s2 = fmaf(z1[k], w2[k * 128 + t], s2);
        z2[t] = fmaxf(s2, 0.f);
    }
    __syncthreads();
    if (t < 250) {
        float s3 = b3[t];
        for (int k = 0; k < 128; ++k) s3 = fmaf(z2[k], w3[k * 250 + t], s3);
        out[g * 250 + t] = s3;
    }
}

extern "C" void kernel_launch(void* const* d_in, const int* in_sizes, int n_in,
                              void* d_out, int out_size, void* d_ws, size_t ws_size,
                              hipStream_t stream) {
    const float* x     = (const float*)d_in[0];
    const int* ei      = (const int*)d_in[1];
    const int* batch   = (const int*)d_in[2];
    const float* w1a   = (const float*)d_in[3];
    const float* b1a   = (const float*)d_in[4];
    const float* w1b   = (const float*)d_in[5];
    const float* b1b   = (const float*)d_in[6];
    const float* W_in  = (const float*)d_in[7];
    const float* b_in  = (const float*)d_in[8];
    const float* W_out = (const float*)d_in[9];
    const float* b_out = (const float*)d_in[10];
    const float* gamma = (const float*)d_in[11];
    const float* beta  = (const float*)d_in[12];
    const float* l1w   = (const float*)d_in[13];
    const float* l1b   = (const float*)d_in[14];
    const float* l2w   = (const float*)d_in[15];
    const float* l2b   = (const float*)d_in[16];
    const float* l3w   = (const float*)d_in[17];
    const float* l3b   = (const float*)d_in[18];

    const int N = in_sizes[2];
    const int E = in_sizes[1] / 2;
    const int* srcv = ei;
    const int* dstv = ei + E;

    // ---- workspace layout (~82 MB) ----
    u16* B0 = (u16*)d_ws;                       // N*256 bf16 (agg out, then pre-BN z)
    u16* B1 = B0 + (size_t)N * 256;             // N*256 bf16 (hidden)
    u16* B2 = B1 + (size_t)N * 256;             // N*256 bf16 (post-BN H)
    u16* Wt = B2 + (size_t)N * 256;             // 8*65536 bf16 transposed weights
    float* stats = (float*)(Wt + 8 * 65536);    // 512
    float* pmax  = stats + 512;                 // 16384
    float* psum  = pmax + GNUM * 256;           // 16384
    float* acc   = psum + GNUM * 256;           // 32768
    float* cnt   = acc + GNUM * 512;            // 64
    int* deg    = (int*)(cnt + GNUM);           // N
    int* part   = deg + N;                      // N
    int* bsum   = part + N;                     // 256
    int* offs   = bsum + 256;                   // N+1
    int* cursor = offs + N + 1;                 // N+1
    int* eidx   = cursor + N + 1;               // E

    int nb256 = (N + 255) / 256;
    int nbM   = (N + 127) / 128;
    int nb64  = (N + 63) / 64;
    int eb    = (E + 255) / 256;

    // --- init + CSR build + per-graph counts ---
    zero_i<<<nb256, 256, 0, stream>>>(deg, N);
    zero_f<<<(GNUM * 512 + GNUM + 255) / 256, 256, 0, stream>>>(acc, GNUM * 512 + GNUM);
    deg_kernel<<<eb, 256, 0, stream>>>(dstv, deg, E);
    scan_block<<<nb256, 256, 0, stream>>>(deg, part, bsum, N);
    scan_bsum<<<1, 256, 0, stream>>>(bsum, nb256);
    scan_fix<<<nb256, 256, 0, stream>>>(part, bsum, offs, cursor, N);
    fill_kernel<<<eb, 256, 0, stream>>>(srcv, dstv, cursor, eidx, E);
    cnt_kernel<<<(nb64 + 255) / 256, 256, 0, stream>>>(batch, cnt, N);

    // --- convert+transpose all 8 weight matrices once ---
    transw<<<128, 256, 0, stream>>>(w1a, Wt + 0 * 65536, 128);
    transw<<<256, 256, 0, stream>>>(w1b, Wt + 1 * 65536, 256);
    for (int i = 0; i < 3; ++i) {
        transw<<<256, 256, 0, stream>>>(W_in  + (size_t)i * 65536, Wt + (2 + i) * 65536, 256);
        transw<<<256, 256, 0, stream>>>(W_out + (size_t)i * 65536, Wt + (5 + i) * 65536, 256);
    }

    for (int L = 0; L < 4; ++L) {
        zero_f<<<(33280 + 255) / 256, 256, 0, stream>>>(stats, 33280);  // stats+pmax+psum
        if (L == 0) {
            agg_f32<<<N, 64, 0, stream>>>(x, offs, eidx, B0, N);
            gemm_mfma<128, true ><<<dim3(nbM, 2), 256, 0, stream>>>(B0, Wt + 0 * 65536, b1a, B1, N);
            gemm_mfma<256, false><<<dim3(nbM, 2), 256, 0, stream>>>(B1, Wt + 1 * 65536, b1b, B0, N);
        } else {
            agg_bf16<<<N, 128, 0, stream>>>(B2, offs, eidx, B0, N);
            gemm_mfma<256, true ><<<dim3(nbM, 2), 256, 0, stream>>>(
                B0, Wt + (size_t)(2 + L - 1) * 65536, b_in + (L - 1) * 256, B1, N);
            gemm_mfma<256, false><<<dim3(nbM, 2), 256, 0, stream>>>(
                B1, Wt + (size_t)(5 + L - 1) * 65536, b_out + (L - 1) * 256, B0, N);
        }
        bn_stats<<<256, 256, 0, stream>>>(B0, stats, N);
        bn_pool<<<nb64, 256, 0, stream>>>(B0, stats, gamma + L * 256, beta + L * 256,
                                          batch, B2, pmax, psum, N);
        acc_update<<<(GNUM * 512) / 256, 256, 0, stream>>>(pmax, psum, cnt, acc);
    }
    readout_kernel<<<GNUM, 256, 0, stream>>>(acc, l1w, l1b, l2w, l2b, l3w, l3b,
                                             (float*)d_out);
}

// Round 4
// 1028.480 us; speedup vs baseline: 1.1471x; 1.1471x over previous
//
#include <hip/hip_runtime.h>
#include <hip/hip_bf16.h>

#define GNUM 64
#define BN_EPS 1e-5f

typedef unsigned short u16;
typedef unsigned int u32;
typedef __attribute__((ext_vector_type(8))) short short8;
typedef __attribute__((ext_vector_type(4))) float f32x4;

__device__ inline float bflo(u32 u) { union { u32 i; float f; } v; v.i = u << 16; return v.f; }
__device__ inline float bfhi(u32 u) { union { u32 i; float f; } v; v.i = u & 0xFFFF0000u; return v.f; }
__device__ inline u16 f2bf(float f) {
    union { float f; u32 i; } v; v.f = f;
    u32 x = v.i;
    return (u16)((x + 0x7FFFu + ((x >> 16) & 1u)) >> 16);  // RNE
}
__device__ inline u32 pack2(float a, float b) { return (u32)f2bf(a) | ((u32)f2bf(b) << 16); }

// ---------------- zero-init ----------------
__global__ void zero_f(float* __restrict__ p, int n) {
    int i = blockIdx.x * 256 + threadIdx.x;
    if (i < n) p[i] = 0.f;
}
__global__ void zero_i(int* __restrict__ p, int n) {
    int i = blockIdx.x * 256 + threadIdx.x;
    if (i < n) p[i] = 0;
}

// ---------------- CSR build ----------------
__global__ void deg_kernel(const int* __restrict__ dst, int* __restrict__ deg, int E) {
    int e = blockIdx.x * 256 + threadIdx.x;
    if (e < E) atomicAdd(&deg[dst[e]], 1);
}

__global__ void scan_block(const int* __restrict__ deg, int* __restrict__ part,
                           int* __restrict__ bsum, int n) {
    __shared__ int tmp[256];
    int i = blockIdx.x * 256 + threadIdx.x;
    int v = (i < n) ? deg[i] : 0;
    tmp[threadIdx.x] = v;
    __syncthreads();
    for (int off = 1; off < 256; off <<= 1) {
        int x = 0;
        if (threadIdx.x >= off) x = tmp[threadIdx.x - off];
        __syncthreads();
        tmp[threadIdx.x] += x;
        __syncthreads();
    }
    if (i < n) part[i] = tmp[threadIdx.x];
    if (threadIdx.x == 255) bsum[blockIdx.x] = tmp[255];
}

__global__ void scan_bsum(int* __restrict__ bsum, int nb) {
    __shared__ int tmp[256];
    int v = (threadIdx.x < nb) ? bsum[threadIdx.x] : 0;
    tmp[threadIdx.x] = v;
    __syncthreads();
    for (int off = 1; off < 256; off <<= 1) {
        int x = 0;
        if (threadIdx.x >= off) x = tmp[threadIdx.x - off];
        __syncthreads();
        tmp[threadIdx.x] += x;
        __syncthreads();
    }
    if (threadIdx.x < nb) bsum[threadIdx.x] = tmp[threadIdx.x];
}

__global__ void scan_fix(const int* __restrict__ part, const int* __restrict__ bsum,
                         int* __restrict__ offs, int* __restrict__ cursor, int n) {
    int i = blockIdx.x * 256 + threadIdx.x;
    if (i >= n) return;
    int add = (blockIdx.x > 0) ? bsum[blockIdx.x - 1] : 0;
    int incl = part[i] + add;
    offs[i + 1] = incl;
    cursor[i + 1] = incl;
    if (i == 0) { offs[0] = 0; cursor[0] = 0; }
}

__global__ void fill_kernel(const int* __restrict__ src, const int* __restrict__ dst,
                            int* __restrict__ cursor, int* __restrict__ eidx, int E) {
    int e = blockIdx.x * 256 + threadIdx.x;
    if (e >= E) return;
    int d = dst[e];
    int p = atomicAdd(&cursor[d], 1);
    eidx[p] = src[e];
}

__global__ void cnt_kernel(const int* __restrict__ batch, float* __restrict__ cnt, int Nn) {
    int tid = blockIdx.x * blockDim.x + threadIdx.x;
    int s = tid * 64;
    if (s >= Nn) return;
    int e = min(s + 64, Nn);
    int cur = batch[s]; int run = 0;
    for (int r = s; r < e; ++r) {
        int b = batch[r];
        if (b != cur) { atomicAdd(&cnt[cur], (float)run); cur = b; run = 0; }
        run++;
    }
    atomicAdd(&cnt[cur], (float)run);
}

// ---------------- x fp32 -> bf16 ----------------
__global__ void cvt_x(const float* __restrict__ x, u16* __restrict__ xb, int total4) {
    int i = blockIdx.x * 256 + threadIdx.x;
    if (i >= total4) return;
    float4 v = *(const float4*)&x[i * 4];
    uint2 o;
    o.x = pack2(v.x, v.y);
    o.y = pack2(v.z, v.w);
    *(uint2*)&xb[i * 4] = o;
}

// ---------------- weight -> MFMA-fragment-ordered bf16 ----------------
// Wp short8 index o = ((t*(K/32) + kc)*8 + jf)*64 + l; element e:
//   k = kc*32 + (l>>4)*8 + e,  col = t*128 + jf*16 + (l&15)
template<int K>
__global__ void transw_frag(const float* __restrict__ W, u16* __restrict__ Wp) {
    int o = blockIdx.x * 256 + threadIdx.x;
    if (o >= K * 32) return;
    int l = o & 63;
    int q1 = o >> 6;
    int jf = q1 & 7;
    int q2 = q1 >> 3;
    const int KC = K / 32;
    int kc = q2 & (KC - 1);
    int t = q2 / KC;
    int kbase = kc * 32 + ((l >> 4) << 3);
    int col = t * 128 + jf * 16 + (l & 15);
#pragma unroll
    for (int e = 0; e < 8; ++e)
        Wp[(size_t)o * 8 + e] = f2bf(W[(size_t)(kbase + e) * 256 + col]);
}

// ---------------- aggregation: z = h + sum_{j->i} h_j (CSR pull), bf16 ----------------
template<int F>
__global__ void agg_bf16(const u16* __restrict__ h, const int* __restrict__ offs,
                         const int* __restrict__ eidx, u16* __restrict__ z, int Nn) {
    int n = blockIdx.x;                 // one block per node, F/2 threads
    int c = threadIdx.x << 1;
    u32 u = *(const u32*)&h[(size_t)n * F + c];
    float a0 = bflo(u), a1 = bfhi(u);
    int j1 = offs[n + 1];
    for (int j = offs[n]; j < j1; ++j) {
        int s = eidx[j];
        u32 w = *(const u32*)&h[(size_t)s * F + c];
        a0 += bflo(w); a1 += bfhi(w);
    }
    *(u32*)&z[(size_t)n * F + c] = pack2(a0, a1);
}

// ---------------- MFMA bf16 GEMM v2 ----------------
// C[M,256] = (relu?)(A[M,K] @ W + b); A row-major bf16; W pre-permuted (Wp).
// Tile 128(m) x 128(n) per block, grid.y=2. 4 waves: wm=(wave&1)*64, wn=(wave>>1)*64.
// A staged in LDS in fragment-major order (conflict-free write+read);
// B fragments read straight from global (L2-resident).
// STATS: accumulate per-column sum/sumsq of (acc+bias) into stats[512] (pre-BN z).
template<int K, bool RELU, bool STATS>
__global__ __launch_bounds__(256)
void gemm_mfma(const u16* __restrict__ A, const u16* __restrict__ Wp,
               const float* __restrict__ bias, u16* __restrict__ C,
               float* __restrict__ stats, int M) {
    __shared__ u16 As[4096];            // 8 KB: 8 frags x 64 lanes x 16B
    int t = threadIdx.x;
    int m0 = blockIdx.x * 128;
    int n0 = blockIdx.y * 128;
    int lane = t & 63, wave = t >> 6;
    int wm = (wave & 1) << 6, wn = (wave >> 1) << 6;
    int lm = lane & 15, q = lane >> 4;
    const int KC = K / 32;

    f32x4 acc[4][4];
#pragma unroll
    for (int i = 0; i < 4; ++i)
#pragma unroll
        for (int j = 0; j < 4; ++j) acc[i][j] = (f32x4)0.0f;

    // precompute staging addresses
    int c0 = t, c1 = t + 256;           // chunk ids
    int r0 = m0 + ((c0 >> 6) << 4) + (c0 & 15);  // frag*16 + (l&15)
    int r1 = m0 + ((c1 >> 6) << 4) + (c1 & 15);
    if (r0 >= M) r0 = M - 1;
    if (r1 >= M) r1 = M - 1;
    int ko0 = ((c0 >> 4) & 3) << 3;     // (l>>4)*8
    int ko1 = ((c1 >> 4) & 3) << 3;

    for (int kc = 0; kc < KC; ++kc) {
        int k0 = kc * 32;
        __syncthreads();
        uint4 v0 = *(const uint4*)&A[(size_t)r0 * K + k0 + ko0];
        uint4 v1 = *(const uint4*)&A[(size_t)r1 * K + k0 + ko1];
        *(uint4*)&As[c0 * 8] = v0;
        *(uint4*)&As[c1 * 8] = v1;
        __syncthreads();
        short8 af[4], bfr[4];
#pragma unroll
        for (int i = 0; i < 4; ++i) {
            af[i] = *(const short8*)&As[(((wave & 1) << 2) + i) * 512 + lane * 8];
            bfr[i] = *(const short8*)&Wp[((((size_t)blockIdx.y * KC + kc) * 8
                                            + ((wave >> 1) << 2) + i) * 64 + lane) * 8];
        }
#pragma unroll
        for (int i = 0; i < 4; ++i)
#pragma unroll
            for (int j = 0; j < 4; ++j)
                acc[i][j] = __builtin_amdgcn_mfma_f32_16x16x32_bf16(af[i], bfr[j], acc[i][j], 0, 0, 0);
    }

    // epilogue: C/D layout col = lane&15, row = (lane>>4)*4 + reg (m89-verified)
    float s_j[4], q_j[4];
#pragma unroll
    for (int j = 0; j < 4; ++j) {
        int col = n0 + wn + j * 16 + lm;
        float bv = bias[col];
        float ss = 0.f, qq = 0.f;
#pragma unroll
        for (int i = 0; i < 4; ++i) {
#pragma unroll
            for (int r = 0; r < 4; ++r) {
                int row = m0 + wm + i * 16 + q * 4 + r;
                if (row < M) {
                    float v = acc[i][j][r] + bv;
                    if (RELU) v = fmaxf(v, 0.f);
                    C[(size_t)row * 256 + col] = f2bf(v);
                    if (STATS) { ss += v; qq = fmaf(v, v, qq); }
                }
            }
        }
        s_j[j] = ss; q_j[j] = qq;
    }

    if (STATS) {
        float* cs = (float*)As;         // reuse LDS: [0..127]=sum, [128..255]=sumsq (local col)
        __syncthreads();
        cs[t] = 0.f;
        __syncthreads();
#pragma unroll
        for (int j = 0; j < 4; ++j) {
            int lc = wn + j * 16 + lm;  // 0..127
            atomicAdd(&cs[lc], s_j[j]);
            atomicAdd(&cs[128 + lc], q_j[j]);
        }
        __syncthreads();
        if (t < 128)      atomicAdd(&stats[n0 + t], cs[t]);
        else              atomicAdd(&stats[256 + n0 + (t - 128)], cs[t]);
    }
}

// ---------------- BN apply + ReLU + segmented max/sum pool ----------------
__global__ __launch_bounds__(256)
void bn_pool(const u16* __restrict__ Z, const float* __restrict__ stats,
             const float* __restrict__ gamma, const float* __restrict__ beta,
             const int* __restrict__ batch, u16* __restrict__ H,
             float* __restrict__ pool_max, float* __restrict__ pool_sum, int Nn) {
    int col = threadIdx.x;
    int r0 = blockIdx.x * 64;
    if (r0 >= Nn) return;
    float mu = stats[col] / (float)Nn;
    float var = stats[256 + col] / (float)Nn - mu * mu;
    float scale = gamma[col] * rsqrtf(var + BN_EPS);
    float shift = beta[col] - mu * scale;
    int rend = min(r0 + 64, Nn);
    int cur = batch[r0];
    float rmax = 0.f, rsum = 0.f;
    for (int r = r0; r < rend; ++r) {
        int bb = batch[r];
        if (bb != cur) {
            atomicMax((int*)&pool_max[cur * 256 + col], __float_as_int(rmax));
            atomicAdd(&pool_sum[cur * 256 + col], rsum);
            cur = bb; rmax = 0.f; rsum = 0.f;
        }
        float v = fmaf(bflo(Z[(size_t)r * 256 + col]), scale, shift);
        v = fmaxf(v, 0.f);  // >=0 so int atomicMax on float bits is valid
        H[(size_t)r * 256 + col] = f2bf(v);
        rmax = fmaxf(rmax, v); rsum += v;
    }
    atomicMax((int*)&pool_max[cur * 256 + col], __float_as_int(rmax));
    atomicAdd(&pool_sum[cur * 256 + col], rsum);
}

// ---------------- acc += concat(max, mean) ----------------
__global__ void acc_update(const float* __restrict__ pmax, const float* __restrict__ psum,
                           const float* __restrict__ cnt, float* __restrict__ acc) {
    int i = blockIdx.x * 256 + threadIdx.x;  // GNUM*512 total
    int g = i >> 9, c = i & 511;
    float v = (c < 256) ? pmax[g * 256 + c]
                        : psum[g * 256 + (c - 256)] / fmaxf(cnt[g], 1.f);
    acc[i] += v;
}

// ---------------- fused readout MLP (fp32): [64,512]->256->128->250 ----------------
__global__ __launch_bounds__(256)
void readout_kernel(const float* __restrict__ acc,
                    const float* __restrict__ w1, const float* __restrict__ b1,
                    const float* __restrict__ w2, const float* __restrict__ b2,
                    const float* __restrict__ w3, const float* __restrict__ b3,
                    float* __restrict__ out) {
    __shared__ float a[512], z1[256], z2[128];
    int g = blockIdx.x, t = threadIdx.x;
    a[t] = acc[g * 512 + t];
    a[t + 256] = acc[g * 512 + 256 + t];
    __syncthreads();
    float s = b1[t];
    for (int k = 0; k < 512; ++k) s = fmaf(a[k], w1[k * 256 + t], s);
    z1[t] = fmaxf(s, 0.f);
    __syncthreads();
    if (t < 128) {
        float s2 = b2[t];
        for (int k = 0; k < 256; ++k) s2 = fmaf(z1[k], w2[k * 128 + t], s2);
        z2[t] = fmaxf(s2, 0.f);
    }
    __syncthreads();
    if (t < 250) {
        float s3 = b3[t];
        for (int k = 0; k < 128; ++k) s3 = fmaf(z2[k], w3[k * 250 + t], s3);
        out[g * 250 + t] = s3;
    }
}

extern "C" void kernel_launch(void* const* d_in, const int* in_sizes, int n_in,
                              void* d_out, int out_size, void* d_ws, size_t ws_size,
                              hipStream_t stream) {
    const float* x     = (const float*)d_in[0];
    const int* ei      = (const int*)d_in[1];
    const int* batch   = (const int*)d_in[2];
    const float* w1a   = (const float*)d_in[3];
    const float* b1a   = (const float*)d_in[4];
    const float* w1b   = (const float*)d_in[5];
    const float* b1b   = (const float*)d_in[6];
    const float* W_in  = (const float*)d_in[7];
    const float* b_in  = (const float*)d_in[8];
    const float* W_out = (const float*)d_in[9];
    const float* b_out = (const float*)d_in[10];
    const float* gamma = (const float*)d_in[11];
    const float* beta  = (const float*)d_in[12];
    const float* l1w   = (const float*)d_in[13];
    const float* l1b   = (const float*)d_in[14];
    const float* l2w   = (const float*)d_in[15];
    const float* l2b   = (const float*)d_in[16];
    const float* l3w   = (const float*)d_in[17];
    const float* l3b   = (const float*)d_in[18];

    const int N = in_sizes[2];
    const int E = in_sizes[1] / 2;
    const int* srcv = ei;
    const int* dstv = ei + E;

    // ---- workspace layout (~82 MB) ----
    u16* B0 = (u16*)d_ws;                       // N*256 bf16
    u16* B1 = B0 + (size_t)N * 256;             // N*256 bf16 (first half doubles as Xb)
    u16* B2 = B1 + (size_t)N * 256;             // N*256 bf16 (post-BN H)
    u16* Xb = B1;                               // N*128 bf16, consumed before B1 written
    u16* Wp = B2 + (size_t)N * 256;             // 32768 + 7*65536 u16 frag-ordered weights
    float* stats = (float*)(Wp + 32768 + 7 * 65536);  // 512
    float* pmax  = stats + 512;                 // 16384
    float* psum  = pmax + GNUM * 256;           // 16384
    float* acc   = psum + GNUM * 256;           // 32768
    float* cnt   = acc + GNUM * 512;            // 64
    int* deg    = (int*)(cnt + GNUM);           // N
    int* part   = deg + N;                      // N
    int* bsum   = part + N;                     // 256
    int* offs   = bsum + 256;                   // N+1
    int* cursor = offs + N + 1;                 // N+1
    int* eidx   = cursor + N + 1;               // E

    int nb256 = (N + 255) / 256;
    int nbM   = (N + 127) / 128;
    int nb64  = (N + 63) / 64;
    int eb    = (E + 255) / 256;

    // --- init + CSR build + per-graph counts ---
    zero_i<<<nb256, 256, 0, stream>>>(deg, N);
    zero_f<<<(GNUM * 512 + GNUM + 255) / 256, 256, 0, stream>>>(acc, GNUM * 512 + GNUM);
    deg_kernel<<<eb, 256, 0, stream>>>(dstv, deg, E);
    scan_block<<<nb256, 256, 0, stream>>>(deg, part, bsum, N);
    scan_bsum<<<1, 256, 0, stream>>>(bsum, nb256);
    scan_fix<<<nb256, 256, 0, stream>>>(part, bsum, offs, cursor, N);
    fill_kernel<<<eb, 256, 0, stream>>>(srcv, dstv, cursor, eidx, E);
    cnt_kernel<<<(nb64 + 255) / 256, 256, 0, stream>>>(batch, cnt, N);

    // --- x -> bf16; weights -> fragment-ordered bf16 ---
    cvt_x<<<(N * 128 / 4 + 255) / 256, 256, 0, stream>>>(x, Xb, N * 128 / 4);
    u16* Wp1 = Wp + 32768;                      // 7 K=256 matrices after the K=128 one
    transw_frag<128><<<(128 * 32 + 255) / 256, 256, 0, stream>>>(w1a, Wp);
    transw_frag<256><<<(256 * 32 + 255) / 256, 256, 0, stream>>>(w1b, Wp1);
    for (int i = 0; i < 3; ++i) {
        transw_frag<256><<<(256 * 32 + 255) / 256, 256, 0, stream>>>(
            W_in + (size_t)i * 65536, Wp1 + (size_t)(1 + i) * 65536);
        transw_frag<256><<<(256 * 32 + 255) / 256, 256, 0, stream>>>(
            W_out + (size_t)i * 65536, Wp1 + (size_t)(4 + i) * 65536);
    }

    for (int L = 0; L < 4; ++L) {
        zero_f<<<(33280 + 255) / 256, 256, 0, stream>>>(stats, 33280);  // stats+pmax+psum
        if (L == 0) {
            agg_bf16<128><<<N, 64, 0, stream>>>(Xb, offs, eidx, B0, N);
            gemm_mfma<128, true, false><<<dim3(nbM, 2), 256, 0, stream>>>(
                B0, Wp, b1a, B1, nullptr, N);
            gemm_mfma<256, false, true><<<dim3(nbM, 2), 256, 0, stream>>>(
                B1, Wp1, b1b, B0, stats, N);
        } else {
            agg_bf16<256><<<N, 128, 0, stream>>>(B2, offs, eidx, B0, N);
            gemm_mfma<256, true, false><<<dim3(nbM, 2), 256, 0, stream>>>(
                B0, Wp1 + (size_t)(1 + L - 1) * 65536, b_in + (L - 1) * 256, B1, nullptr, N);
            gemm_mfma<256, false, true><<<dim3(nbM, 2), 256, 0, stream>>>(
                B1, Wp1 + (size_t)(4 + L - 1) * 65536, b_out + (L - 1) * 256, B0, stats, N);
        }
        bn_pool<<<nb64, 256, 0, stream>>>(B0, stats, gamma + L * 256, beta + L * 256,
                                          batch, B2, pmax, psum, N);
        acc_update<<<(GNUM * 512) / 256, 256, 0, stream>>>(pmax, psum, cnt, acc);
    }
    readout_kernel<<<GNUM, 256, 0, stream>>>(acc, l1w, l1b, l2w, l2b, l3w, l3b,
                                             (float*)d_out);
}

// Round 5
// 992.156 us; speedup vs baseline: 1.1891x; 1.0366x over previous
//
#include <hip/hip_runtime.h>
#include <hip/hip_bf16.h>

#define GNUM 64
#define BN_EPS 1e-5f

typedef unsigned short u16;
typedef unsigned int u32;
typedef __attribute__((ext_vector_type(8))) short short8;
typedef __attribute__((ext_vector_type(4))) float f32x4;

__device__ inline float bflo(u32 u) { union { u32 i; float f; } v; v.i = u << 16; return v.f; }
__device__ inline float bfhi(u32 u) { union { u32 i; float f; } v; v.i = u & 0xFFFF0000u; return v.f; }
__device__ inline u16 f2bf(float f) {
    union { float f; u32 i; } v; v.f = f;
    u32 x = v.i;
    return (u16)((x + 0x7FFFu + ((x >> 16) & 1u)) >> 16);  // RNE
}
__device__ inline u32 pack2(float a, float b) { return (u32)f2bf(a) | ((u32)f2bf(b) << 16); }

// ---------------- zero-init ----------------
__global__ void zero_f(float* __restrict__ p, int n) {
    int i = blockIdx.x * 256 + threadIdx.x;
    if (i < n) p[i] = 0.f;
}
__global__ void zero_i(int* __restrict__ p, int n) {
    int i = blockIdx.x * 256 + threadIdx.x;
    if (i < n) p[i] = 0;
}

// ---------------- CSR build ----------------
__global__ void deg_kernel(const int* __restrict__ dst, int* __restrict__ deg, int E) {
    int e = blockIdx.x * 256 + threadIdx.x;
    if (e < E) atomicAdd(&deg[dst[e]], 1);
}

__global__ void scan_block(const int* __restrict__ deg, int* __restrict__ part,
                           int* __restrict__ bsum, int n) {
    __shared__ int tmp[256];
    int i = blockIdx.x * 256 + threadIdx.x;
    int v = (i < n) ? deg[i] : 0;
    tmp[threadIdx.x] = v;
    __syncthreads();
    for (int off = 1; off < 256; off <<= 1) {
        int x = 0;
        if (threadIdx.x >= off) x = tmp[threadIdx.x - off];
        __syncthreads();
        tmp[threadIdx.x] += x;
        __syncthreads();
    }
    if (i < n) part[i] = tmp[threadIdx.x];
    if (threadIdx.x == 255) bsum[blockIdx.x] = tmp[255];
}

__global__ void scan_bsum(int* __restrict__ bsum, int nb) {
    __shared__ int tmp[256];
    int v = (threadIdx.x < nb) ? bsum[threadIdx.x] : 0;
    tmp[threadIdx.x] = v;
    __syncthreads();
    for (int off = 1; off < 256; off <<= 1) {
        int x = 0;
        if (threadIdx.x >= off) x = tmp[threadIdx.x - off];
        __syncthreads();
        tmp[threadIdx.x] += x;
        __syncthreads();
    }
    if (threadIdx.x < nb) bsum[threadIdx.x] = tmp[threadIdx.x];
}

__global__ void scan_fix(const int* __restrict__ part, const int* __restrict__ bsum,
                         int* __restrict__ offs, int* __restrict__ cursor, int n) {
    int i = blockIdx.x * 256 + threadIdx.x;
    if (i >= n) return;
    int add = (blockIdx.x > 0) ? bsum[blockIdx.x - 1] : 0;
    int incl = part[i] + add;
    offs[i + 1] = incl;
    cursor[i + 1] = incl;
    if (i == 0) { offs[0] = 0; cursor[0] = 0; }
}

__global__ void fill_kernel(const int* __restrict__ src, const int* __restrict__ dst,
                            int* __restrict__ cursor, int* __restrict__ eidx, int E) {
    int e = blockIdx.x * 256 + threadIdx.x;
    if (e >= E) return;
    int d = dst[e];
    int p = atomicAdd(&cursor[d], 1);
    eidx[p] = src[e];
}

__global__ void cnt_kernel(const int* __restrict__ batch, float* __restrict__ cnt, int Nn) {
    int tid = blockIdx.x * blockDim.x + threadIdx.x;
    int s = tid * 64;
    if (s >= Nn) return;
    int e = min(s + 64, Nn);
    int cur = batch[s]; int run = 0;
    for (int r = s; r < e; ++r) {
        int b = batch[r];
        if (b != cur) { atomicAdd(&cnt[cur], (float)run); cur = b; run = 0; }
        run++;
    }
    atomicAdd(&cnt[cur], (float)run);
}

// ---------------- x fp32 -> bf16 ----------------
__global__ void cvt_x(const float* __restrict__ x, u16* __restrict__ xb, int total4) {
    int i = blockIdx.x * 256 + threadIdx.x;
    if (i >= total4) return;
    float4 v = *(const float4*)&x[i * 4];
    uint2 o;
    o.x = pack2(v.x, v.y);
    o.y = pack2(v.z, v.w);
    *(uint2*)&xb[i * 4] = o;
}

// ---------------- weight -> MFMA-fragment-ordered bf16 ----------------
// Wp short8 index o = ((t*(K/32) + kc)*8 + jf)*64 + l; element e:
//   k = kc*32 + (l>>4)*8 + e,  col = t*128 + jf*16 + (l&15)
template<int K>
__global__ void transw_frag(const float* __restrict__ W, u16* __restrict__ Wp) {
    int o = blockIdx.x * 256 + threadIdx.x;
    if (o >= K * 32) return;
    int l = o & 63;
    int q1 = o >> 6;
    int jf = q1 & 7;
    int q2 = q1 >> 3;
    const int KC = K / 32;
    int kc = q2 & (KC - 1);
    int t = q2 / KC;
    int kbase = kc * 32 + ((l >> 4) << 3);
    int col = t * 128 + jf * 16 + (l & 15);
#pragma unroll
    for (int e = 0; e < 8; ++e)
        Wp[(size_t)o * 8 + e] = f2bf(W[(size_t)(kbase + e) * 256 + col]);
}

// ---------------- aggregation v2: edge-parallel gather ----------------
// z[n] = h[n] + sum_{j->n} h[src_j].  Block=256 threads = G groups x CH chunks,
// CH = F/8 (16B chunks per row), G = 256/CH edge groups. Tree-reduce in LDS.
template<int F>
__global__ __launch_bounds__(256)
void agg2(const u16* __restrict__ h, const int* __restrict__ offs,
          const int* __restrict__ eidx, u16* __restrict__ z, int Nn) {
    const int CH = F / 8;
    const int G = 256 / CH;
    __shared__ float red[2048];         // 256 threads x 8 floats
    int n = blockIdx.x;
    int t = threadIdx.x;
    int cc = t & (CH - 1);
    int g = t / CH;

    float a[8];
    if (g == 0) {
        uint4 v = *(const uint4*)&h[(size_t)n * F + cc * 8];
        a[0] = bflo(v.x); a[1] = bfhi(v.x); a[2] = bflo(v.y); a[3] = bfhi(v.y);
        a[4] = bflo(v.z); a[5] = bfhi(v.z); a[6] = bflo(v.w); a[7] = bfhi(v.w);
    } else {
#pragma unroll
        for (int e = 0; e < 8; ++e) a[e] = 0.f;
    }
    int j1 = offs[n + 1];
    for (int j = offs[n] + g; j < j1; j += G) {
        int s = eidx[j];
        uint4 v = *(const uint4*)&h[(size_t)s * F + cc * 8];
        a[0] += bflo(v.x); a[1] += bfhi(v.x); a[2] += bflo(v.y); a[3] += bfhi(v.y);
        a[4] += bflo(v.z); a[5] += bfhi(v.z); a[6] += bflo(v.w); a[7] += bfhi(v.w);
    }
    float4* rp = (float4*)red;
    rp[t * 2]     = make_float4(a[0], a[1], a[2], a[3]);
    rp[t * 2 + 1] = make_float4(a[4], a[5], a[6], a[7]);
    __syncthreads();
    for (int s = G >> 1; s > 0; s >>= 1) {
        if (g < s) {
            int p = (t + s * CH) * 2;
            float4 x0 = rp[p], x1 = rp[p + 1];
            float4 y0 = rp[t * 2], y1 = rp[t * 2 + 1];
            y0.x += x0.x; y0.y += x0.y; y0.z += x0.z; y0.w += x0.w;
            y1.x += x1.x; y1.y += x1.y; y1.z += x1.z; y1.w += x1.w;
            rp[t * 2] = y0; rp[t * 2 + 1] = y1;
        }
        __syncthreads();
    }
    if (g == 0) {
        float4 y0 = rp[t * 2], y1 = rp[t * 2 + 1];
        uint4 o;
        o.x = pack2(y0.x, y0.y); o.y = pack2(y0.z, y0.w);
        o.z = pack2(y1.x, y1.y); o.w = pack2(y1.z, y1.w);
        *(uint4*)&z[(size_t)n * F + cc * 8] = o;
    }
}

// ---------------- MFMA bf16 GEMM v2 (round-4, conflict-free) ----------------
template<int K, bool RELU, bool STATS>
__global__ __launch_bounds__(256)
void gemm_mfma(const u16* __restrict__ A, const u16* __restrict__ Wp,
               const float* __restrict__ bias, u16* __restrict__ C,
               float* __restrict__ stats, int M) {
    __shared__ u16 As[4096];            // 8 KB: 8 frags x 64 lanes x 16B
    int t = threadIdx.x;
    int m0 = blockIdx.x * 128;
    int n0 = blockIdx.y * 128;
    int lane = t & 63, wave = t >> 6;
    int wm = (wave & 1) << 6, wn = (wave >> 1) << 6;
    int lm = lane & 15, q = lane >> 4;
    const int KC = K / 32;

    f32x4 acc[4][4];
#pragma unroll
    for (int i = 0; i < 4; ++i)
#pragma unroll
        for (int j = 0; j < 4; ++j) acc[i][j] = (f32x4)0.0f;

    int c0 = t, c1 = t + 256;
    int r0 = m0 + ((c0 >> 6) << 4) + (c0 & 15);
    int r1 = m0 + ((c1 >> 6) << 4) + (c1 & 15);
    if (r0 >= M) r0 = M - 1;
    if (r1 >= M) r1 = M - 1;
    int ko0 = ((c0 >> 4) & 3) << 3;
    int ko1 = ((c1 >> 4) & 3) << 3;

    for (int kc = 0; kc < KC; ++kc) {
        int k0 = kc * 32;
        __syncthreads();
        uint4 v0 = *(const uint4*)&A[(size_t)r0 * K + k0 + ko0];
        uint4 v1 = *(const uint4*)&A[(size_t)r1 * K + k0 + ko1];
        *(uint4*)&As[c0 * 8] = v0;
        *(uint4*)&As[c1 * 8] = v1;
        __syncthreads();
        short8 af[4], bfr[4];
#pragma unroll
        for (int i = 0; i < 4; ++i) {
            af[i] = *(const short8*)&As[(((wave & 1) << 2) + i) * 512 + lane * 8];
            bfr[i] = *(const short8*)&Wp[((((size_t)blockIdx.y * KC + kc) * 8
                                            + ((wave >> 1) << 2) + i) * 64 + lane) * 8];
        }
#pragma unroll
        for (int i = 0; i < 4; ++i)
#pragma unroll
            for (int j = 0; j < 4; ++j)
                acc[i][j] = __builtin_amdgcn_mfma_f32_16x16x32_bf16(af[i], bfr[j], acc[i][j], 0, 0, 0);
    }

    float s_j[4], q_j[4];
#pragma unroll
    for (int j = 0; j < 4; ++j) {
        int col = n0 + wn + j * 16 + lm;
        float bv = bias[col];
        float ss = 0.f, qq = 0.f;
#pragma unroll
        for (int i = 0; i < 4; ++i) {
#pragma unroll
            for (int r = 0; r < 4; ++r) {
                int row = m0 + wm + i * 16 + q * 4 + r;
                if (row < M) {
                    float v = acc[i][j][r] + bv;
                    if (RELU) v = fmaxf(v, 0.f);
                    C[(size_t)row * 256 + col] = f2bf(v);
                    if (STATS) { ss += v; qq = fmaf(v, v, qq); }
                }
            }
        }
        s_j[j] = ss; q_j[j] = qq;
    }

    if (STATS) {
        float* cs = (float*)As;
        __syncthreads();
        cs[t] = 0.f;
        __syncthreads();
#pragma unroll
        for (int j = 0; j < 4; ++j) {
            int lc = wn + j * 16 + lm;
            atomicAdd(&cs[lc], s_j[j]);
            atomicAdd(&cs[128 + lc], q_j[j]);
        }
        __syncthreads();
        if (t < 128)      atomicAdd(&stats[n0 + t], cs[t]);
        else              atomicAdd(&stats[256 + n0 + (t - 128)], cs[t]);
    }
}

// ---------------- BN apply + ReLU + segmented max/sum pool ----------------
__global__ __launch_bounds__(256)
void bn_pool(const u16* __restrict__ Z, const float* __restrict__ stats,
             const float* __restrict__ gamma, const float* __restrict__ beta,
             const int* __restrict__ batch, u16* __restrict__ H,
             float* __restrict__ pool_max, float* __restrict__ pool_sum, int Nn) {
    int col = threadIdx.x;
    int r0 = blockIdx.x * 64;
    if (r0 >= Nn) return;
    float mu = stats[col] / (float)Nn;
    float var = stats[256 + col] / (float)Nn - mu * mu;
    float scale = gamma[col] * rsqrtf(var + BN_EPS);
    float shift = beta[col] - mu * scale;
    int rend = min(r0 + 64, Nn);
    int cur = batch[r0];
    float rmax = 0.f, rsum = 0.f;
    for (int r = r0; r < rend; ++r) {
        int bb = batch[r];
        if (bb != cur) {
            atomicMax((int*)&pool_max[cur * 256 + col], __float_as_int(rmax));
            atomicAdd(&pool_sum[cur * 256 + col], rsum);
            cur = bb; rmax = 0.f; rsum = 0.f;
        }
        float v = fmaf(bflo(Z[(size_t)r * 256 + col]), scale, shift);
        v = fmaxf(v, 0.f);  // >=0 so int atomicMax on float bits is valid
        H[(size_t)r * 256 + col] = f2bf(v);
        rmax = fmaxf(rmax, v); rsum += v;
    }
    atomicMax((int*)&pool_max[cur * 256 + col], __float_as_int(rmax));
    atomicAdd(&pool_sum[cur * 256 + col], rsum);
}

// ---------------- acc += concat(max, mean); reset pmax/psum/stats for next layer ----------------
__global__ void acc_update(float* __restrict__ pmax, float* __restrict__ psum,
                           const float* __restrict__ cnt, float* __restrict__ acc,
                           float* __restrict__ stats) {
    int i = blockIdx.x * 256 + threadIdx.x;  // GNUM*512 total
    int g = i >> 9, c = i & 511;
    float v;
    if (c < 256) {
        v = pmax[g * 256 + c];
        pmax[g * 256 + c] = 0.f;
    } else {
        int cc = c - 256;
        v = psum[g * 256 + cc] / fmaxf(cnt[g], 1.f);
        psum[g * 256 + cc] = 0.f;
    }
    acc[i] += v;
    if (i < 512) stats[i] = 0.f;
}

// ---------------- fused readout MLP (fp32): [64,512]->256->128->250 ----------------
__global__ __launch_bounds__(256)
void readout_kernel(const float* __restrict__ acc,
                    const float* __restrict__ w1, const float* __restrict__ b1,
                    const float* __restrict__ w2, const float* __restrict__ b2,
                    const float* __restrict__ w3, const float* __restrict__ b3,
                    float* __restrict__ out) {
    __shared__ float a[512], z1[256], z2[128];
    int g = blockIdx.x, t = threadIdx.x;
    a[t] = acc[g * 512 + t];
    a[t + 256] = acc[g * 512 + 256 + t];
    __syncthreads();
    float s = b1[t];
    for (int k = 0; k < 512; ++k) s = fmaf(a[k], w1[k * 256 + t], s);
    z1[t] = fmaxf(s, 0.f);
    __syncthreads();
    if (t < 128) {
        float s2 = b2[t];
        for (int k = 0; k < 256; ++k) s2 = fmaf(z1[k], w2[k * 128 + t], s2);
        z2[t] = fmaxf(s2, 0.f);
    }
    __syncthreads();
    if (t < 250) {
        float s3 = b3[t];
        for (int k = 0; k < 128; ++k) s3 = fmaf(z2[k], w3[k * 250 + t], s3);
        out[g * 250 + t] = s3;
    }
}

extern "C" void kernel_launch(void* const* d_in, const int* in_sizes, int n_in,
                              void* d_out, int out_size, void* d_ws, size_t ws_size,
                              hipStream_t stream) {
    const float* x     = (const float*)d_in[0];
    const int* ei      = (const int*)d_in[1];
    const int* batch   = (const int*)d_in[2];
    const float* w1a   = (const float*)d_in[3];
    const float* b1a   = (const float*)d_in[4];
    const float* w1b   = (const float*)d_in[5];
    const float* b1b   = (const float*)d_in[6];
    const float* W_in  = (const float*)d_in[7];
    const float* b_in  = (const float*)d_in[8];
    const float* W_out = (const float*)d_in[9];
    const float* b_out = (const float*)d_in[10];
    const float* gamma = (const float*)d_in[11];
    const float* beta  = (const float*)d_in[12];
    const float* l1w   = (const float*)d_in[13];
    const float* l1b   = (const float*)d_in[14];
    const float* l2w   = (const float*)d_in[15];
    const float* l2b   = (const float*)d_in[16];
    const float* l3w   = (const float*)d_in[17];
    const float* l3b   = (const float*)d_in[18];

    const int N = in_sizes[2];
    const int E = in_sizes[1] / 2;
    const int* srcv = ei;
    const int* dstv = ei + E;

    // ---- workspace layout (~82 MB) ----
    u16* B0 = (u16*)d_ws;                       // N*256 bf16
    u16* B1 = B0 + (size_t)N * 256;             // N*256 bf16 (first half doubles as Xb)
    u16* B2 = B1 + (size_t)N * 256;             // N*256 bf16 (post-BN H)
    u16* Xb = B1;                               // N*128 bf16, consumed before B1 written
    u16* Wp = B2 + (size_t)N * 256;             // 32768 + 7*65536 u16 frag-ordered weights
    float* stats = (float*)(Wp + 32768 + 7 * 65536);  // 512   } contiguous fp32 block:
    float* pmax  = stats + 512;                 // 16384        } stats,pmax,psum,acc,cnt
    float* psum  = pmax + GNUM * 256;           // 16384
    float* acc   = psum + GNUM * 256;           // 32768
    float* cnt   = acc + GNUM * 512;            // 64
    int* deg    = (int*)(cnt + GNUM);           // N
    int* part   = deg + N;                      // N
    int* bsum   = part + N;                     // 256
    int* offs   = bsum + 256;                   // N+1
    int* cursor = offs + N + 1;                 // N+1
    int* eidx   = cursor + N + 1;               // E

    int nb256 = (N + 255) / 256;
    int nbM   = (N + 127) / 128;
    int nb64  = (N + 63) / 64;
    int eb    = (E + 255) / 256;
    const int FTOT = 512 + GNUM * 256 * 2 + GNUM * 512 + GNUM;  // 66112

    // --- init + CSR build + per-graph counts ---
    zero_i<<<nb256, 256, 0, stream>>>(deg, N);
    zero_f<<<(FTOT + 255) / 256, 256, 0, stream>>>(stats, FTOT);
    deg_kernel<<<eb, 256, 0, stream>>>(dstv, deg, E);
    scan_block<<<nb256, 256, 0, stream>>>(deg, part, bsum, N);
    scan_bsum<<<1, 256, 0, stream>>>(bsum, nb256);
    scan_fix<<<nb256, 256, 0, stream>>>(part, bsum, offs, cursor, N);
    fill_kernel<<<eb, 256, 0, stream>>>(srcv, dstv, cursor, eidx, E);
    cnt_kernel<<<(nb64 + 255) / 256, 256, 0, stream>>>(batch, cnt, N);

    // --- x -> bf16; weights -> fragment-ordered bf16 ---
    cvt_x<<<(N * 128 / 4 + 255) / 256, 256, 0, stream>>>(x, Xb, N * 128 / 4);
    u16* Wp1 = Wp + 32768;                      // 7 K=256 matrices after the K=128 one
    transw_frag<128><<<(128 * 32 + 255) / 256, 256, 0, stream>>>(w1a, Wp);
    transw_frag<256><<<(256 * 32 + 255) / 256, 256, 0, stream>>>(w1b, Wp1);
    for (int i = 0; i < 3; ++i) {
        transw_frag<256><<<(256 * 32 + 255) / 256, 256, 0, stream>>>(
            W_in + (size_t)i * 65536, Wp1 + (size_t)(1 + i) * 65536);
        transw_frag<256><<<(256 * 32 + 255) / 256, 256, 0, stream>>>(
            W_out + (size_t)i * 65536, Wp1 + (size_t)(4 + i) * 65536);
    }

    for (int L = 0; L < 4; ++L) {
        if (L == 0) {
            agg2<128><<<N, 256, 0, stream>>>(Xb, offs, eidx, B0, N);
            gemm_mfma<128, true, false><<<dim3(nbM, 2), 256, 0, stream>>>(
                B0, Wp, b1a, B1, nullptr, N);
            gemm_mfma<256, false, true><<<dim3(nbM, 2), 256, 0, stream>>>(
                B1, Wp1, b1b, B0, stats, N);
        } else {
            agg2<256><<<N, 256, 0, stream>>>(B2, offs, eidx, B0, N);
            gemm_mfma<256, true, false><<<dim3(nbM, 2), 256, 0, stream>>>(
                B0, Wp1 + (size_t)(1 + L - 1) * 65536, b_in + (L - 1) * 256, B1, nullptr, N);
            gemm_mfma<256, false, true><<<dim3(nbM, 2), 256, 0, stream>>>(
                B1, Wp1 + (size_t)(4 + L - 1) * 65536, b_out + (L - 1) * 256, B0, stats, N);
        }
        bn_pool<<<nb64, 256, 0, stream>>>(B0, stats, gamma + L * 256, beta + L * 256,
                                          batch, B2, pmax, psum, N);
        acc_update<<<(GNUM * 512) / 256, 256, 0, stream>>>(pmax, psum, cnt, acc, stats);
    }
    readout_kernel<<<GNUM, 256, 0, stream>>>(acc, l1w, l1b, l2w, l2b, l3w, l3b,
                                             (float*)d_out);
}

// Round 6
// 913.107 us; speedup vs baseline: 1.2920x; 1.0866x over previous
//
#include <hip/hip_runtime.h>
#include <hip/hip_bf16.h>

#define GNUM 64
#define BN_EPS 1e-5f

typedef unsigned short u16;
typedef unsigned int u32;
typedef __attribute__((ext_vector_type(8))) short short8;
typedef __attribute__((ext_vector_type(4))) float f32x4;

__device__ inline float bflo(u32 u) { union { u32 i; float f; } v; v.i = u << 16; return v.f; }
__device__ inline float bfhi(u32 u) { union { u32 i; float f; } v; v.i = u & 0xFFFF0000u; return v.f; }
__device__ inline u16 f2bf(float f) {
    union { float f; u32 i; } v; v.f = f;
    u32 x = v.i;
    return (u16)((x + 0x7FFFu + ((x >> 16) & 1u)) >> 16);  // RNE
}
__device__ inline u32 pack2(float a, float b) { return (u32)f2bf(a) | ((u32)f2bf(b) << 16); }
__device__ inline void acc8(float* a, uint4 v) {
    a[0] += bflo(v.x); a[1] += bfhi(v.x); a[2] += bflo(v.y); a[3] += bfhi(v.y);
    a[4] += bflo(v.z); a[5] += bfhi(v.z); a[6] += bflo(v.w); a[7] += bfhi(v.w);
}

// ---------------- zero-init ----------------
__global__ void zero_f(float* __restrict__ p, int n) {
    int i = blockIdx.x * 256 + threadIdx.x;
    if (i < n) p[i] = 0.f;
}
__global__ void zero_i(int* __restrict__ p, int n) {
    int i = blockIdx.x * 256 + threadIdx.x;
    if (i < n) p[i] = 0;
}

// ---------------- CSR build ----------------
__global__ void deg_kernel(const int* __restrict__ dst, int* __restrict__ deg, int E) {
    int e = blockIdx.x * 256 + threadIdx.x;
    if (e < E) atomicAdd(&deg[dst[e]], 1);
}

__global__ void scan_block(const int* __restrict__ deg, int* __restrict__ part,
                           int* __restrict__ bsum, int n) {
    __shared__ int tmp[256];
    int i = blockIdx.x * 256 + threadIdx.x;
    int v = (i < n) ? deg[i] : 0;
    tmp[threadIdx.x] = v;
    __syncthreads();
    for (int off = 1; off < 256; off <<= 1) {
        int x = 0;
        if (threadIdx.x >= off) x = tmp[threadIdx.x - off];
        __syncthreads();
        tmp[threadIdx.x] += x;
        __syncthreads();
    }
    if (i < n) part[i] = tmp[threadIdx.x];
    if (threadIdx.x == 255) bsum[blockIdx.x] = tmp[255];
}

__global__ void scan_bsum(int* __restrict__ bsum, int nb) {
    __shared__ int tmp[256];
    int v = (threadIdx.x < nb) ? bsum[threadIdx.x] : 0;
    tmp[threadIdx.x] = v;
    __syncthreads();
    for (int off = 1; off < 256; off <<= 1) {
        int x = 0;
        if (threadIdx.x >= off) x = tmp[threadIdx.x - off];
        __syncthreads();
        tmp[threadIdx.x] += x;
        __syncthreads();
    }
    if (threadIdx.x < nb) bsum[threadIdx.x] = tmp[threadIdx.x];
}

__global__ void scan_fix(const int* __restrict__ part, const int* __restrict__ bsum,
                         int* __restrict__ offs, int* __restrict__ cursor, int n) {
    int i = blockIdx.x * 256 + threadIdx.x;
    if (i >= n) return;
    int add = (blockIdx.x > 0) ? bsum[blockIdx.x - 1] : 0;
    int incl = part[i] + add;
    offs[i + 1] = incl;
    cursor[i + 1] = incl;
    if (i == 0) { offs[0] = 0; cursor[0] = 0; }
}

__global__ void fill_kernel(const int* __restrict__ src, const int* __restrict__ dst,
                            int* __restrict__ cursor, int* __restrict__ eidx, int E) {
    int e = blockIdx.x * 256 + threadIdx.x;
    if (e >= E) return;
    int d = dst[e];
    int p = atomicAdd(&cursor[d], 1);
    eidx[p] = src[e];
}

__global__ void cnt_kernel(const int* __restrict__ batch, float* __restrict__ cnt, int Nn) {
    int tid = blockIdx.x * blockDim.x + threadIdx.x;
    int s = tid * 64;
    if (s >= Nn) return;
    int e = min(s + 64, Nn);
    int cur = batch[s]; int run = 0;
    for (int r = s; r < e; ++r) {
        int b = batch[r];
        if (b != cur) { atomicAdd(&cnt[cur], (float)run); cur = b; run = 0; }
        run++;
    }
    atomicAdd(&cnt[cur], (float)run);
}

// ---------------- x fp32 -> bf16 ----------------
__global__ void cvt_x(const float* __restrict__ x, u16* __restrict__ xb, int total4) {
    int i = blockIdx.x * 256 + threadIdx.x;
    if (i >= total4) return;
    float4 v = *(const float4*)&x[i * 4];
    uint2 o;
    o.x = pack2(v.x, v.y);
    o.y = pack2(v.z, v.w);
    *(uint2*)&xb[i * 4] = o;
}

// ---------------- weight -> MFMA-fragment-ordered bf16 ----------------
// Wp short8 index o = ((t*(K/32) + kc)*8 + jf)*64 + l; element e:
//   k = kc*32 + (l>>4)*8 + e,  col = t*128 + jf*16 + (l&15)
template<int K>
__global__ void transw_frag(const float* __restrict__ W, u16* __restrict__ Wp) {
    int o = blockIdx.x * 256 + threadIdx.x;
    if (o >= K * 32) return;
    int l = o & 63;
    int q1 = o >> 6;
    int jf = q1 & 7;
    int q2 = q1 >> 3;
    const int KC = K / 32;
    int kc = q2 & (KC - 1);
    int t = q2 / KC;
    int kbase = kc * 32 + ((l >> 4) << 3);
    int col = t * 128 + jf * 16 + (l & 15);
#pragma unroll
    for (int e = 0; e < 8; ++e)
        Wp[(size_t)o * 8 + e] = f2bf(W[(size_t)(kbase + e) * 256 + col]);
}

// ---------------- aggregation v3: wave-per-node, LDS-free, 4-deep MLP ----------------
// z[n] = h[n] + sum_{j->n} h[src_j]. 64-lane wave per node; lanes = CH chunks x G groups.
// Edge loop unrolled x4 (4 independent gathers in flight); cross-group shuffle reduce.
template<int F>
__global__ __launch_bounds__(256)
void agg3(const u16* __restrict__ h, const int* __restrict__ offs,
          const int* __restrict__ eidx, u16* __restrict__ z, int Nn) {
    const int CH = F / 8;               // 16B chunks per row (16 or 32)
    const int G = 64 / CH;              // edge groups per wave (4 or 2)
    int lane = threadIdx.x & 63;
    int n = blockIdx.x * 4 + (threadIdx.x >> 6);
    if (n >= Nn) return;
    int cc = lane & (CH - 1);
    int g = lane / CH;
    const u16* hp = h + cc * 8;

    float a[8] = {0.f, 0.f, 0.f, 0.f, 0.f, 0.f, 0.f, 0.f};
    if (g == 0) acc8(a, *(const uint4*)&hp[(size_t)n * F]);   // self term

    int j1 = offs[n + 1];
    int j = offs[n] + g;
    for (; j + 3 * G < j1; j += 4 * G) {
        int s0 = eidx[j], s1 = eidx[j + G], s2 = eidx[j + 2 * G], s3 = eidx[j + 3 * G];
        uint4 v0 = *(const uint4*)&hp[(size_t)s0 * F];
        uint4 v1 = *(const uint4*)&hp[(size_t)s1 * F];
        uint4 v2 = *(const uint4*)&hp[(size_t)s2 * F];
        uint4 v3 = *(const uint4*)&hp[(size_t)s3 * F];
        acc8(a, v0); acc8(a, v1); acc8(a, v2); acc8(a, v3);
    }
    for (; j < j1; j += G) {
        uint4 v = *(const uint4*)&hp[(size_t)eidx[j] * F];
        acc8(a, v);
    }
#pragma unroll
    for (int off = 32; off >= CH; off >>= 1)
#pragma unroll
        for (int e = 0; e < 8; ++e) a[e] += __shfl_down(a[e], off, 64);
    if (g == 0) {
        uint4 o;
        o.x = pack2(a[0], a[1]); o.y = pack2(a[2], a[3]);
        o.z = pack2(a[4], a[5]); o.w = pack2(a[6], a[7]);
        *(uint4*)&z[(size_t)n * F + cc * 8] = o;
    }
}

// ---------------- MFMA bf16 GEMM v2 (round-4, conflict-free) ----------------
template<int K, bool RELU, bool STATS>
__global__ __launch_bounds__(256)
void gemm_mfma(const u16* __restrict__ A, const u16* __restrict__ Wp,
               const float* __restrict__ bias, u16* __restrict__ C,
               float* __restrict__ stats, int M) {
    __shared__ u16 As[4096];            // 8 KB: 8 frags x 64 lanes x 16B
    int t = threadIdx.x;
    int m0 = blockIdx.x * 128;
    int n0 = blockIdx.y * 128;
    int lane = t & 63, wave = t >> 6;
    int wm = (wave & 1) << 6, wn = (wave >> 1) << 6;
    int lm = lane & 15, q = lane >> 4;
    const int KC = K / 32;

    f32x4 acc[4][4];
#pragma unroll
    for (int i = 0; i < 4; ++i)
#pragma unroll
        for (int j = 0; j < 4; ++j) acc[i][j] = (f32x4)0.0f;

    int c0 = t, c1 = t + 256;
    int r0 = m0 + ((c0 >> 6) << 4) + (c0 & 15);
    int r1 = m0 + ((c1 >> 6) << 4) + (c1 & 15);
    if (r0 >= M) r0 = M - 1;
    if (r1 >= M) r1 = M - 1;
    int ko0 = ((c0 >> 4) & 3) << 3;
    int ko1 = ((c1 >> 4) & 3) << 3;

    for (int kc = 0; kc < KC; ++kc) {
        int k0 = kc * 32;
        __syncthreads();
        uint4 v0 = *(const uint4*)&A[(size_t)r0 * K + k0 + ko0];
        uint4 v1 = *(const uint4*)&A[(size_t)r1 * K + k0 + ko1];
        *(uint4*)&As[c0 * 8] = v0;
        *(uint4*)&As[c1 * 8] = v1;
        __syncthreads();
        short8 af[4], bfr[4];
#pragma unroll
        for (int i = 0; i < 4; ++i) {
            af[i] = *(const short8*)&As[(((wave & 1) << 2) + i) * 512 + lane * 8];
            bfr[i] = *(const short8*)&Wp[((((size_t)blockIdx.y * KC + kc) * 8
                                            + ((wave >> 1) << 2) + i) * 64 + lane) * 8];
        }
#pragma unroll
        for (int i = 0; i < 4; ++i)
#pragma unroll
            for (int j = 0; j < 4; ++j)
                acc[i][j] = __builtin_amdgcn_mfma_f32_16x16x32_bf16(af[i], bfr[j], acc[i][j], 0, 0, 0);
    }

    float s_j[4], q_j[4];
#pragma unroll
    for (int j = 0; j < 4; ++j) {
        int col = n0 + wn + j * 16 + lm;
        float bv = bias[col];
        float ss = 0.f, qq = 0.f;
#pragma unroll
        for (int i = 0; i < 4; ++i) {
#pragma unroll
            for (int r = 0; r < 4; ++r) {
                int row = m0 + wm + i * 16 + q * 4 + r;
                if (row < M) {
                    float v = acc[i][j][r] + bv;
                    if (RELU) v = fmaxf(v, 0.f);
                    C[(size_t)row * 256 + col] = f2bf(v);
                    if (STATS) { ss += v; qq = fmaf(v, v, qq); }
                }
            }
        }
        s_j[j] = ss; q_j[j] = qq;
    }

    if (STATS) {
        float* cs = (float*)As;
        __syncthreads();
        cs[t] = 0.f;
        __syncthreads();
#pragma unroll
        for (int j = 0; j < 4; ++j) {
            int lc = wn + j * 16 + lm;
            atomicAdd(&cs[lc], s_j[j]);
            atomicAdd(&cs[128 + lc], q_j[j]);
        }
        __syncthreads();
        if (t < 128)      atomicAdd(&stats[n0 + t], cs[t]);
        else              atomicAdd(&stats[256 + n0 + (t - 128)], cs[t]);
    }
}

// ---------------- BN apply + ReLU + segmented max/sum pool ----------------
__global__ __launch_bounds__(256)
void bn_pool(const u16* __restrict__ Z, const float* __restrict__ stats,
             const float* __restrict__ gamma, const float* __restrict__ beta,
             const int* __restrict__ batch, u16* __restrict__ H,
             float* __restrict__ pool_max, float* __restrict__ pool_sum, int Nn) {
    int col = threadIdx.x;
    int r0 = blockIdx.x * 64;
    if (r0 >= Nn) return;
    float mu = stats[col] / (float)Nn;
    float var = stats[256 + col] / (float)Nn - mu * mu;
    float scale = gamma[col] * rsqrtf(var + BN_EPS);
    float shift = beta[col] - mu * scale;
    int rend = min(r0 + 64, Nn);
    int cur = batch[r0];
    float rmax = 0.f, rsum = 0.f;
    for (int r = r0; r < rend; ++r) {
        int bb = batch[r];
        if (bb != cur) {
            atomicMax((int*)&pool_max[cur * 256 + col], __float_as_int(rmax));
            atomicAdd(&pool_sum[cur * 256 + col], rsum);
            cur = bb; rmax = 0.f; rsum = 0.f;
        }
        float v = fmaf(bflo(Z[(size_t)r * 256 + col]), scale, shift);
        v = fmaxf(v, 0.f);  // >=0 so int atomicMax on float bits is valid
        H[(size_t)r * 256 + col] = f2bf(v);
        rmax = fmaxf(rmax, v); rsum += v;
    }
    atomicMax((int*)&pool_max[cur * 256 + col], __float_as_int(rmax));
    atomicAdd(&pool_sum[cur * 256 + col], rsum);
}

// ---------------- acc += concat(max, mean); reset pmax/psum/stats for next layer ----------------
__global__ void acc_update(float* __restrict__ pmax, float* __restrict__ psum,
                           const float* __restrict__ cnt, float* __restrict__ acc,
                           float* __restrict__ stats) {
    int i = blockIdx.x * 256 + threadIdx.x;  // GNUM*512 total
    int g = i >> 9, c = i & 511;
    float v;
    if (c < 256) {
        v = pmax[g * 256 + c];
        pmax[g * 256 + c] = 0.f;
    } else {
        int cc = c - 256;
        v = psum[g * 256 + cc] / fmaxf(cnt[g], 1.f);
        psum[g * 256 + cc] = 0.f;
    }
    acc[i] += v;
    if (i < 512) stats[i] = 0.f;
}

// ---------------- fused readout MLP (fp32): [64,512]->256->128->250 ----------------
__global__ __launch_bounds__(256)
void readout_kernel(const float* __restrict__ acc,
                    const float* __restrict__ w1, const float* __restrict__ b1,
                    const float* __restrict__ w2, const float* __restrict__ b2,
                    const float* __restrict__ w3, const float* __restrict__ b3,
                    float* __restrict__ out) {
    __shared__ float a[512], z1[256], z2[128];
    int g = blockIdx.x, t = threadIdx.x;
    a[t] = acc[g * 512 + t];
    a[t + 256] = acc[g * 512 + 256 + t];
    __syncthreads();
    float s = b1[t];
    for (int k = 0; k < 512; ++k) s = fmaf(a[k], w1[k * 256 + t], s);
    z1[t] = fmaxf(s, 0.f);
    __syncthreads();
    if (t < 128) {
        float s2 = b2[t];
        for (int k = 0; k < 256; ++k) s2 = fmaf(z1[k], w2[k * 128 + t], s2);
        z2[t] = fmaxf(s2, 0.f);
    }
    __syncthreads();
    if (t < 250) {
        float s3 = b3[t];
        for (int k = 0; k < 128; ++k) s3 = fmaf(z2[k], w3[k * 250 + t], s3);
        out[g * 250 + t] = s3;
    }
}

extern "C" void kernel_launch(void* const* d_in, const int* in_sizes, int n_in,
                              void* d_out, int out_size, void* d_ws, size_t ws_size,
                              hipStream_t stream) {
    const float* x     = (const float*)d_in[0];
    const int* ei      = (const int*)d_in[1];
    const int* batch   = (const int*)d_in[2];
    const float* w1a   = (const float*)d_in[3];
    const float* b1a   = (const float*)d_in[4];
    const float* w1b   = (const float*)d_in[5];
    const float* b1b   = (const float*)d_in[6];
    const float* W_in  = (const float*)d_in[7];
    const float* b_in  = (const float*)d_in[8];
    const float* W_out = (const float*)d_in[9];
    const float* b_out = (const float*)d_in[10];
    const float* gamma = (const float*)d_in[11];
    const float* beta  = (const float*)d_in[12];
    const float* l1w   = (const float*)d_in[13];
    const float* l1b   = (const float*)d_in[14];
    const float* l2w   = (const float*)d_in[15];
    const float* l2b   = (const float*)d_in[16];
    const float* l3w   = (const float*)d_in[17];
    const float* l3b   = (const float*)d_in[18];

    const int N = in_sizes[2];
    const int E = in_sizes[1] / 2;
    const int* srcv = ei;
    const int* dstv = ei + E;

    // ---- workspace layout (~82 MB) ----
    u16* B0 = (u16*)d_ws;                       // N*256 bf16
    u16* B1 = B0 + (size_t)N * 256;             // N*256 bf16 (first half doubles as Xb)
    u16* B2 = B1 + (size_t)N * 256;             // N*256 bf16 (post-BN H)
    u16* Xb = B1;                               // N*128 bf16, consumed before B1 written
    u16* Wp = B2 + (size_t)N * 256;             // 32768 + 7*65536 u16 frag-ordered weights
    float* stats = (float*)(Wp + 32768 + 7 * 65536);  // 512   } contiguous fp32 block:
    float* pmax  = stats + 512;                 // 16384        } stats,pmax,psum,acc,cnt
    float* psum  = pmax + GNUM * 256;           // 16384
    float* acc   = psum + GNUM * 256;           // 32768
    float* cnt   = acc + GNUM * 512;            // 64
    int* deg    = (int*)(cnt + GNUM);           // N
    int* part   = deg + N;                      // N
    int* bsum   = part + N;                     // 256
    int* offs   = bsum + 256;                   // N+1
    int* cursor = offs + N + 1;                 // N+1
    int* eidx   = cursor + N + 1;               // E

    int nb256 = (N + 255) / 256;
    int nbM   = (N + 127) / 128;
    int nb64  = (N + 63) / 64;
    int nbW   = (N + 3) / 4;
    int eb    = (E + 255) / 256;
    const int FTOT = 512 + GNUM * 256 * 2 + GNUM * 512 + GNUM;  // 66112

    // --- init + CSR build + per-graph counts ---
    zero_i<<<nb256, 256, 0, stream>>>(deg, N);
    zero_f<<<(FTOT + 255) / 256, 256, 0, stream>>>(stats, FTOT);
    deg_kernel<<<eb, 256, 0, stream>>>(dstv, deg, E);
    scan_block<<<nb256, 256, 0, stream>>>(deg, part, bsum, N);
    scan_bsum<<<1, 256, 0, stream>>>(bsum, nb256);
    scan_fix<<<nb256, 256, 0, stream>>>(part, bsum, offs, cursor, N);
    fill_kernel<<<eb, 256, 0, stream>>>(srcv, dstv, cursor, eidx, E);
    cnt_kernel<<<(nb64 + 255) / 256, 256, 0, stream>>>(batch, cnt, N);

    // --- x -> bf16; weights -> fragment-ordered bf16 ---
    cvt_x<<<(N * 128 / 4 + 255) / 256, 256, 0, stream>>>(x, Xb, N * 128 / 4);
    u16* Wp1 = Wp + 32768;                      // 7 K=256 matrices after the K=128 one
    transw_frag<128><<<(128 * 32 + 255) / 256, 256, 0, stream>>>(w1a, Wp);
    transw_frag<256><<<(256 * 32 + 255) / 256, 256, 0, stream>>>(w1b, Wp1);
    for (int i = 0; i < 3; ++i) {
        transw_frag<256><<<(256 * 32 + 255) / 256, 256, 0, stream>>>(
            W_in + (size_t)i * 65536, Wp1 + (size_t)(1 + i) * 65536);
        transw_frag<256><<<(256 * 32 + 255) / 256, 256, 0, stream>>>(
            W_out + (size_t)i * 65536, Wp1 + (size_t)(4 + i) * 65536);
    }

    for (int L = 0; L < 4; ++L) {
        if (L == 0) {
            agg3<128><<<nbW, 256, 0, stream>>>(Xb, offs, eidx, B0, N);
            gemm_mfma<128, true, false><<<dim3(nbM, 2), 256, 0, stream>>>(
                B0, Wp, b1a, B1, nullptr, N);
            gemm_mfma<256, false, true><<<dim3(nbM, 2), 256, 0, stream>>>(
                B1, Wp1, b1b, B0, stats, N);
        } else {
            agg3<256><<<nbW, 256, 0, stream>>>(B2, offs, eidx, B0, N);
            gemm_mfma<256, true, false><<<dim3(nbM, 2), 256, 0, stream>>>(
                B0, Wp1 + (size_t)(1 + L - 1) * 65536, b_in + (L - 1) * 256, B1, nullptr, N);
            gemm_mfma<256, false, true><<<dim3(nbM, 2), 256, 0, stream>>>(
                B1, Wp1 + (size_t)(4 + L - 1) * 65536, b_out + (L - 1) * 256, B0, stats, N);
        }
        bn_pool<<<nb64, 256, 0, stream>>>(B0, stats, gamma + L * 256, beta + L * 256,
                                          batch, B2, pmax, psum, N);
        acc_update<<<(GNUM * 512) / 256, 256, 0, stream>>>(pmax, psum, cnt, acc, stats);
    }
    readout_kernel<<<GNUM, 256, 0, stream>>>(acc, l1w, l1b, l2w, l2b, l3w, l3b,
                                             (float*)d_out);
}